// Round 1
// baseline (2050.881 us; speedup 1.0000x reference)
//
#include <hip/hip_runtime.h>
#include <stdint.h>

typedef unsigned short ush;
typedef unsigned int u32;
typedef __attribute__((ext_vector_type(8))) short short8;
typedef __attribute__((ext_vector_type(4))) float f32x4;

#define DEVI static __device__ __forceinline__

constexpr int CC = 128, CH = 128;
constexpr int CS = 131072;           // H*W*Z per (n,c)
constexpr float BNEPS = 1e-5f;

DEVI ush f2bf(float f) {
  u32 u = __float_as_uint(f);
  u += 0x7FFF + ((u >> 16) & 1);     // RNE
  return (ush)(u >> 16);
}
DEVI float bf2f(ush h) { return __uint_as_float(((u32)h) << 16); }

// tanh-form GELU; |err| vs exact-erf gelu < 1e-3, final path scaled by ls_g~1e-3 -> negligible
DEVI float gelu_tanh(float v) {
  float y = 0.79788456f * (v + 0.044715f * v * v * v);
  float e = __expf(2.0f * y);
  return v * (1.0f - 1.0f / (e + 1.0f));
}

DEVI float wave_sum(float v) {
  v += __shfl_xor(v, 1);  v += __shfl_xor(v, 2);  v += __shfl_xor(v, 4);
  v += __shfl_xor(v, 8);  v += __shfl_xor(v, 16); v += __shfl_xor(v, 32);
  return v;
}

// ---------------------------------------------------------------------------
// K1: 4-branch depthwise conv, stats only (per-branch per-channel sum/sumsq)
// block = (hb, c, n), 512 thr = (w 0..127) x (hh 0..3); 8 output h-rows/block
// ---------------------------------------------------------------------------
__global__ __launch_bounds__(512) void k_conv_stats(
    const float* __restrict__ x, const float* __restrict__ lk_w,
    const float* __restrict__ dw5_w, const float* __restrict__ dw3a_w,
    const float* __restrict__ dw3b_w, float* __restrict__ part1)
{
  __shared__ float tile[14][134][8];
  __shared__ float4 coef[49][4];
  __shared__ float red[8][8];
  const int hb = blockIdx.x, c = blockIdx.y, n = blockIdx.z, tid = threadIdx.x;

  if (tid < 196) {
    int tap = tid >> 2, b = tid & 3;
    int dh = tap / 7, dw = tap % 7;
    const float* p = nullptr;
    if (b == 0) p = lk_w + c*147 + dh*21 + dw*3;
    else if (b == 1) { if (dh>=1 && dh<=5 && dw>=1 && dw<=5) p = dw5_w + c*75 + (dh-1)*15 + (dw-1)*3; }
    else if (b == 2) { if ((dh&1) && (dw&1)) p = dw3a_w + c*27 + ((dh-1)>>1)*9 + ((dw-1)>>1)*3; }
    else             { if (dh%3==0 && dw%3==0) p = dw3b_w + c*27 + (dh/3)*9 + (dw/3)*3; }
    float4 cf = make_float4(0.f,0.f,0.f,0.f);
    if (p) cf = make_float4(p[0], p[1], p[2], 0.f);
    coef[tap][b] = cf;
  }

  const float* xc = x + ((size_t)(n*CC + c)) * CS;
  #pragma unroll
  for (int i = 0; i < 7; i++) {
    int idx = i*512 + tid;                 // 3584 float4 = 14 rows * 1024 floats
    int row = idx >> 8, f4 = idx & 255;
    int wc2 = f4 >> 1, zh = f4 & 1;
    int hin = hb*8 - 3 + row;
    float4 val = make_float4(0.f,0.f,0.f,0.f);
    if (hin >= 0 && hin < CH) val = *(const float4*)(xc + (size_t)hin*1024 + wc2*8 + zh*4);
    *(float4*)&tile[row][3+wc2][zh*4] = val;
  }
  if (tid < 168) {                         // zero the w-halo
    int row = tid / 12, q = tid % 12;
    int wp = q >> 1, zh = q & 1;
    int wslot = (wp < 3) ? wp : (128 + wp);
    *(float4*)&tile[row][wslot][zh*4] = make_float4(0.f,0.f,0.f,0.f);
  }
  __syncthreads();

  const int wc = tid & 127, hh = tid >> 7;
  float sm0=0,sm1=0,sm2=0,sm3=0, sq0=0,sq1=0,sq2=0,sq3=0;
  #pragma unroll 1
  for (int rr = 0; rr < 2; rr++) {
    const int oh = hh + rr*4;
    float a0[8]={0,0,0,0,0,0,0,0}, a1[8]={0,0,0,0,0,0,0,0};
    float a2[8]={0,0,0,0,0,0,0,0}, a3[8]={0,0,0,0,0,0,0,0};
    #pragma unroll 1
    for (int dh = 0; dh < 7; dh++) {
      const bool h5 = (dh >= 1 && dh <= 5);
      const bool hodd = (dh & 1) != 0;
      const bool h3 = (dh == 0 || dh == 3 || dh == 6);
      #pragma unroll
      for (int dw = 0; dw < 7; dw++) {
        const float* vp = &tile[oh+dh][wc+dw][0];
        float4 lo = *(const float4*)vp;
        float4 hi = *(const float4*)(vp + 4);
        float v[10];
        v[0]=0.f; v[1]=lo.x; v[2]=lo.y; v[3]=lo.z; v[4]=lo.w;
        v[5]=hi.x; v[6]=hi.y; v[7]=hi.z; v[8]=hi.w; v[9]=0.f;
        const int tap = dh*7 + dw;
        {
          float4 cf = coef[tap][0];
          #pragma unroll
          for (int z = 0; z < 8; z++) a0[z] += cf.x*v[z] + cf.y*v[z+1] + cf.z*v[z+2];
        }
        if (h5 && dw >= 1 && dw <= 5) {
          float4 cf = coef[tap][1];
          #pragma unroll
          for (int z = 0; z < 8; z++) a1[z] += cf.x*v[z] + cf.y*v[z+1] + cf.z*v[z+2];
        }
        if (hodd && (dw & 1)) {
          float4 cf = coef[tap][2];
          #pragma unroll
          for (int z = 0; z < 8; z++) a2[z] += cf.x*v[z] + cf.y*v[z+1] + cf.z*v[z+2];
        }
        if (h3 && (dw == 0 || dw == 3 || dw == 6)) {
          float4 cf = coef[tap][3];
          #pragma unroll
          for (int z = 0; z < 8; z++) a3[z] += cf.x*v[z] + cf.y*v[z+1] + cf.z*v[z+2];
        }
      }
    }
    #pragma unroll
    for (int z = 0; z < 8; z++) {
      sm0+=a0[z]; sq0+=a0[z]*a0[z]; sm1+=a1[z]; sq1+=a1[z]*a1[z];
      sm2+=a2[z]; sq2+=a2[z]*a2[z]; sm3+=a3[z]; sq3+=a3[z]*a3[z];
    }
  }
  float vals[8] = {sm0,sm1,sm2,sm3,sq0,sq1,sq2,sq3};
  #pragma unroll
  for (int j = 0; j < 8; j++) vals[j] = wave_sum(vals[j]);
  const int wid = tid >> 6, lane = tid & 63;
  if (lane == 0) {
    #pragma unroll
    for (int j = 0; j < 8; j++) red[wid][j] = vals[j];
  }
  __syncthreads();
  if (tid < 8) {
    float s = 0.f;
    #pragma unroll
    for (int w2 = 0; w2 < 8; w2++) s += red[w2][tid];
    part1[(((size_t)n*CC + c)*16 + hb)*8 + tid] = s;
  }
}

// ---------------------------------------------------------------------------
// K2: reduce branch stats -> BN affines -> combined 7x7x3 kernel + constant T
// ---------------------------------------------------------------------------
__global__ __launch_bounds__(512) void k_branch_reduce(
    const float* __restrict__ part1,
    const float* bn0_w, const float* bn0_b, const float* dbn1_w, const float* dbn1_b,
    const float* dbn2_w, const float* dbn2_b, const float* dbn3_w, const float* dbn3_b,
    const float* lk_w, const float* dw5_w, const float* dw3a_w, const float* dw3b_w,
    float* __restrict__ coef3, float* __restrict__ Tbuf)
{
  __shared__ float sA[4][128], tA[4][128];
  const int tid = threadIdx.x;
  {
    int c = tid >> 2, b = tid & 3;
    float s = 0.f, q = 0.f;
    for (int n = 0; n < 2; n++)
      for (int hb = 0; hb < 16; hb++) {
        const float* p = part1 + (((size_t)n*CC + c)*16 + hb)*8;
        s += p[b]; q += p[4 + b];
      }
    float mean = s * (1.f/262144.f);
    float var  = q * (1.f/262144.f) - mean*mean;
    float g, bb;
    if (b == 0)      { g = bn0_w[c];  bb = bn0_b[c];  }
    else if (b == 1) { g = dbn1_w[c]; bb = dbn1_b[c]; }
    else if (b == 2) { g = dbn2_w[c]; bb = dbn2_b[c]; }
    else             { g = dbn3_w[c]; bb = dbn3_b[c]; }
    float sc = g * rsqrtf(var + BNEPS);
    sA[b][c] = sc;
    tA[b][c] = bb - mean * sc;
  }
  __syncthreads();
  for (int i = tid; i < 128*49; i += 512) {
    int c = i / 49, tap = i % 49;
    int dh = tap / 7, dw = tap % 7;
    float s0 = sA[0][c], s1 = sA[1][c], s2 = sA[2][c], s3 = sA[3][c];
    float kz[3];
    #pragma unroll
    for (int dz = 0; dz < 3; dz++) {
      float v = s0 * lk_w[c*147 + dh*21 + dw*3 + dz];
      if (dh>=1 && dh<=5 && dw>=1 && dw<=5) v += s1 * dw5_w[c*75 + (dh-1)*15 + (dw-1)*3 + dz];
      if ((dh&1) && (dw&1))                 v += s2 * dw3a_w[c*27 + ((dh-1)>>1)*9 + ((dw-1)>>1)*3 + dz];
      if (dh%3==0 && dw%3==0)               v += s3 * dw3b_w[c*27 + (dh/3)*9 + (dw/3)*3 + dz];
      kz[dz] = v;
    }
    *(float4*)(coef3 + (size_t)i*4) = make_float4(kz[0], kz[1], kz[2], 0.f);
  }
  if (tid < 128) Tbuf[tid] = tA[0][tid] + tA[1][tid] + tA[2][tid] + tA[3][tid];
}

// ---------------------------------------------------------------------------
// K3: combined 147-tap conv -> y_pre (bf16, NCS layout) + block-BN/SE partials
// ---------------------------------------------------------------------------
__global__ __launch_bounds__(512) void k_conv_main(
    const float* __restrict__ x, const float* __restrict__ coef3,
    const float* __restrict__ Tbuf, ush* __restrict__ y_pre, float* __restrict__ part2)
{
  __shared__ float tile[14][134][8];
  __shared__ float4 cf3[49];
  __shared__ float red2[8][2];
  __shared__ float Ts_s;
  const int hb = blockIdx.x, c = blockIdx.y, n = blockIdx.z, tid = threadIdx.x;

  if (tid < 49) cf3[tid] = *(const float4*)(coef3 + ((size_t)c*49 + tid)*4);
  if (tid == 64) Ts_s = Tbuf[c];

  const float* xc = x + ((size_t)(n*CC + c)) * CS;
  #pragma unroll
  for (int i = 0; i < 7; i++) {
    int idx = i*512 + tid;
    int row = idx >> 8, f4 = idx & 255;
    int wc2 = f4 >> 1, zh = f4 & 1;
    int hin = hb*8 - 3 + row;
    float4 val = make_float4(0.f,0.f,0.f,0.f);
    if (hin >= 0 && hin < CH) val = *(const float4*)(xc + (size_t)hin*1024 + wc2*8 + zh*4);
    *(float4*)&tile[row][3+wc2][zh*4] = val;
  }
  if (tid < 168) {
    int row = tid / 12, q = tid % 12;
    int wp = q >> 1, zh = q & 1;
    int wslot = (wp < 3) ? wp : (128 + wp);
    *(float4*)&tile[row][wslot][zh*4] = make_float4(0.f,0.f,0.f,0.f);
  }
  __syncthreads();

  const float Tc = Ts_s;
  const int wc = tid & 127, hh = tid >> 7;
  float ssum = 0.f, ssq = 0.f;
  #pragma unroll 1
  for (int rr = 0; rr < 2; rr++) {
    const int oh = hh + rr*4;
    float a0[8] = {0,0,0,0,0,0,0,0};
    #pragma unroll 1
    for (int dh = 0; dh < 7; dh++) {
      #pragma unroll
      for (int dw = 0; dw < 7; dw++) {
        const float* vp = &tile[oh+dh][wc+dw][0];
        float4 lo = *(const float4*)vp;
        float4 hi = *(const float4*)(vp + 4);
        float v[10];
        v[0]=0.f; v[1]=lo.x; v[2]=lo.y; v[3]=lo.z; v[4]=lo.w;
        v[5]=hi.x; v[6]=hi.y; v[7]=hi.z; v[8]=hi.w; v[9]=0.f;
        float4 cf = cf3[dh*7 + dw];
        #pragma unroll
        for (int z = 0; z < 8; z++) a0[z] += cf.x*v[z] + cf.y*v[z+1] + cf.z*v[z+2];
      }
    }
    const int ho = hb*8 + oh;
    ush o8[8];
    #pragma unroll
    for (int z = 0; z < 8; z++) {
      float yv = a0[z] + Tc;
      ssum += yv; ssq += yv*yv;
      o8[z] = f2bf(yv);
    }
    u32 p0 = (u32)o8[0] | ((u32)o8[1] << 16);
    u32 p1 = (u32)o8[2] | ((u32)o8[3] << 16);
    u32 p2 = (u32)o8[4] | ((u32)o8[5] << 16);
    u32 p3 = (u32)o8[6] | ((u32)o8[7] << 16);
    *(uint4*)(y_pre + ((size_t)(n*CC + c))*CS + (size_t)ho*1024 + wc*8) = make_uint4(p0,p1,p2,p3);
  }
  float vs = wave_sum(ssum), vq = wave_sum(ssq);
  const int wid = tid >> 6, lane = tid & 63;
  if (lane == 0) { red2[wid][0] = vs; red2[wid][1] = vq; }
  __syncthreads();
  if (tid < 2) {
    float s = 0.f;
    #pragma unroll
    for (int w2 = 0; w2 < 8; w2++) s += red2[w2][tid];
    part2[(((size_t)n*CC + c)*16 + hb)*2 + tid] = s;
  }
}

// ---------------------------------------------------------------------------
// K4: block-BN stats + SE -> per-(n,c) affine A,B for GEMM1 input folding
// ---------------------------------------------------------------------------
__global__ __launch_bounds__(256) void k_bn_se(
    const float* __restrict__ part2, const float* nrm_w, const float* nrm_b,
    const float* se_dw, const float* se_db, const float* se_uw, const float* se_ub,
    float* __restrict__ ABuf)
{
  __shared__ float pmA[2][128], hA[2][32], alA[128], beA[128];
  const int tid = threadIdx.x;
  if (tid < 128) {
    int c = tid;
    float s=0.f, q=0.f, p0=0.f, p1=0.f;
    for (int n = 0; n < 2; n++)
      for (int hb = 0; hb < 16; hb++) {
        float v = part2[(((size_t)n*CC + c)*16 + hb)*2];
        s += v; q += part2[(((size_t)n*CC + c)*16 + hb)*2 + 1];
        if (n == 0) p0 += v; else p1 += v;
      }
    float m   = s * (1.f/262144.f);
    float var = q * (1.f/262144.f) - m*m;
    float inv = rsqrtf(var + BNEPS);
    float al = nrm_w[c]*inv;
    float be = nrm_b[c] - m*al;
    alA[c] = al; beA[c] = be;
    pmA[0][c] = (p0*(1.f/131072.f) - m)*al + be;
    pmA[1][c] = (p1*(1.f/131072.f) - m)*al + be;
  }
  __syncthreads();
  if (tid < 64) {
    int n = tid >> 5, i = tid & 31;
    float h = se_db[i];
    for (int c2 = 0; c2 < 128; c2++) h += pmA[n][c2]*se_dw[i*128 + c2];
    hA[n][i] = fmaxf(h, 0.f);
  }
  __syncthreads();
  {
    int n = tid >> 7, c = tid & 127;
    float sse = se_ub[c];
    #pragma unroll
    for (int i = 0; i < 32; i++) sse += hA[n][i]*se_uw[c*32 + i];
    ABuf[(n*128 + c)*2 + 0] = alA[c]*sse;
    ABuf[(n*128 + c)*2 + 1] = beA[c]*sse;
  }
}

// ---------------------------------------------------------------------------
// K5: fold A into w1 (bf16, [n][f][c]) and B into beta[n][f]
// ---------------------------------------------------------------------------
__global__ __launch_bounds__(512) void k_w1prep(
    const float* __restrict__ w1, const float* __restrict__ b1,
    const float* __restrict__ ABuf, ush* __restrict__ w1t, float* __restrict__ beta)
{
  const int n = blockIdx.x, tid = threadIdx.x;
  __shared__ float Asc[128], Bsc[128];
  if (tid < 128) { Asc[tid] = ABuf[(n*128 + tid)*2]; Bsc[tid] = ABuf[(n*128 + tid)*2 + 1]; }
  __syncthreads();
  for (int i = tid; i < 512*128; i += 512) {
    int cc = i >> 9, f = i & 511;
    w1t[((size_t)n*512 + f)*128 + cc] = f2bf(w1[cc*512 + f] * Asc[cc]);
  }
  {
    int f = tid;
    float s = b1[f];
    for (int cc = 0; cc < 128; cc++) s += Bsc[cc]*w1[cc*512 + f];
    beta[n*512 + f] = s;
  }
}

// ---------------------------------------------------------------------------
// K6: transpose y_pre (n,c,s) -> y_cl (n,s,c), both bf16
// ---------------------------------------------------------------------------
__global__ __launch_bounds__(256) void k_transpose(
    const ush* __restrict__ y_pre, ush* __restrict__ y_cl)
{
  __shared__ ush ld[32768];
  const int sblk = blockIdx.x, n = blockIdx.y, tid = threadIdx.x;
  #pragma unroll 2
  for (int i = 0; i < 16; i++) {
    int idx = i*256 + tid;                   // 4096: c=idx>>5, s-chunk=idx&31
    int c = idx >> 5, gs = idx & 31;
    uint4 v = *(const uint4*)(y_pre + ((size_t)(n*CC + c))*CS + sblk*256 + gs*8);
    union { uint4 q; ush e[8]; } uu; uu.q = v;
    #pragma unroll
    for (int j = 0; j < 8; j++) {
      int s_l = gs*8 + j;
      int gran = s_l*16 + ((c >> 3) ^ (gs & 7));
      ld[gran*8 + (c & 7)] = uu.e[j];
    }
  }
  __syncthreads();
  #pragma unroll 2
  for (int i = 0; i < 16; i++) {
    int idx = i*256 + tid;                   // s=idx>>4, c-granule=idx&15
    int s_l = idx >> 4, gc = idx & 15;
    int gran = s_l*16 + (gc ^ ((s_l >> 3) & 7));
    uint4 v = *(const uint4*)&ld[gran*8];
    *(uint4*)(y_cl + ((size_t)n*CS + sblk*256 + s_l)*128 + gc*8) = v;
  }
}

// ---------------------------------------------------------------------------
// K7: GEMM1  t[n,s,f] = gelu( y_cl @ w1t_n^T + beta ), bf16 out + GRN partials
// tile 128m x 128f, K=128 single-stage, 4 waves (2x2), T2 XOR-swizzled LDS
// ---------------------------------------------------------------------------
__global__ __launch_bounds__(256) void k_gemm1(
    const ush* __restrict__ y_cl, const ush* __restrict__ w1t,
    const float* __restrict__ beta, ush* __restrict__ tbuf, float* __restrict__ grnp)
{
  __shared__ __align__(16) ush Al[16384];
  __shared__ __align__(16) ush Bl[16384];
  const int mt = blockIdx.x, ft = blockIdx.y, n = blockIdx.z, tid = threadIdx.x;
  const ush* Ab = y_cl + ((size_t)n*CS + (size_t)mt*128) * 128;
  const ush* Bb = w1t + ((size_t)n*512 + (size_t)ft*128) * 128;
  #pragma unroll
  for (int i = 0; i < 8; i++) {
    int g = i*256 + tid;
    int r = g >> 4, cg = g & 15;
    *(uint4*)&Al[r*128 + ((cg ^ (r & 7))*8)] = *(const uint4*)(Ab + (size_t)g*8);
    *(uint4*)&Bl[r*128 + ((cg ^ (r & 7))*8)] = *(const uint4*)(Bb + (size_t)g*8);
  }
  __syncthreads();

  const int wid = tid >> 6, lane = tid & 63;
  const int wm = wid >> 1, wn = wid & 1;
  const int lr = lane & 15, lk = lane >> 4;
  f32x4 acc[4][4] = {};
  #pragma unroll
  for (int kk = 0; kk < 4; kk++) {
    short8 af[4], bfr[4];
    #pragma unroll
    for (int mf = 0; mf < 4; mf++) {
      int row = wm*64 + mf*16 + lr;
      int cg = (kk*4 + lk) ^ (row & 7);
      af[mf] = *(const short8*)&Al[row*128 + cg*8];
    }
    #pragma unroll
    for (int nf = 0; nf < 4; nf++) {
      int row = wn*64 + nf*16 + lr;
      int cg = (kk*4 + lk) ^ (row & 7);
      bfr[nf] = *(const short8*)&Bl[row*128 + cg*8];
    }
    #pragma unroll
    for (int mf = 0; mf < 4; mf++)
      #pragma unroll
      for (int nf = 0; nf < 4; nf++)
        acc[mf][nf] = __builtin_amdgcn_mfma_f32_16x16x32_bf16(af[mf], bfr[nf], acc[mf][nf], 0, 0, 0);
  }

  float bt[4];
  #pragma unroll
  for (int nf = 0; nf < 4; nf++) bt[nf] = beta[n*512 + ft*128 + wn*64 + nf*16 + lr];
  float sq[4] = {0.f,0.f,0.f,0.f};
  #pragma unroll
  for (int mf = 0; mf < 4; mf++)
    #pragma unroll
    for (int nf = 0; nf < 4; nf++)
      #pragma unroll
      for (int r = 0; r < 4; r++) {
        float g = gelu_tanh(acc[mf][nf][r] + bt[nf]);
        sq[nf] += g*g;
        acc[mf][nf][r] = g;
      }
  __syncthreads();                          // everyone done reading Al/Bl
  float* grnl = (float*)Al;                 // [128][2]
  #pragma unroll
  for (int nf = 0; nf < 4; nf++) {
    float v = sq[nf];
    v += __shfl_xor(v, 16); v += __shfl_xor(v, 32);
    if (lane < 16) grnl[(wn*64 + nf*16 + lane)*2 + wm] = v;
  }
  #pragma unroll
  for (int mf = 0; mf < 4; mf++)
    #pragma unroll
    for (int nf = 0; nf < 4; nf++)
      #pragma unroll
      for (int r = 0; r < 4; r++) {
        int ml = wm*64 + mf*16 + lk*4 + r;
        int fl = wn*64 + nf*16 + lr;
        Bl[ml*128 + (fl ^ (((ml >> 2) & 3) << 4))] = f2bf(acc[mf][nf][r]);
      }
  __syncthreads();
  #pragma unroll
  for (int i = 0; i < 8; i++) {
    int idx = i*256 + tid;
    int m = idx >> 4, gc = idx & 15;
    uint4 v = *(const uint4*)&Bl[m*128 + ((gc ^ (((m >> 2) & 3) << 1))*8)];
    *(uint4*)(tbuf + ((size_t)n*CS + (size_t)mt*128 + m)*512 + ft*128 + gc*8) = v;
  }
  if (tid < 128) grnp[(size_t)mt*1024 + n*512 + ft*128 + tid] = grnl[tid*2] + grnl[tid*2+1];
}

// ---------------------------------------------------------------------------
// K8: GRN: Gx -> Nx -> a[n][f] = grn_g*Nx + 1
// ---------------------------------------------------------------------------
__global__ __launch_bounds__(1024) void k_grn(
    const float* __restrict__ grnp, const float* __restrict__ grn_g, float* __restrict__ aBuf)
{
  __shared__ float wsum[16], gm[2];
  const int tid = threadIdx.x;
  float s = 0.f;
  for (int mtv = 0; mtv < 1024; mtv++) s += grnp[(size_t)mtv*1024 + tid];
  float Gx = sqrtf(s);
  float v = wave_sum(Gx);
  if ((tid & 63) == 0) wsum[tid >> 6] = v;
  __syncthreads();
  if (tid < 2) {
    float m = 0.f;
    #pragma unroll
    for (int w2 = 0; w2 < 8; w2++) m += wsum[tid*8 + w2];
    gm[tid] = m * (1.f/512.f) + 1e-6f;
  }
  __syncthreads();
  int n = tid >> 9, f = tid & 511;
  aBuf[tid] = grn_g[f] * (Gx / gm[n]) + 1.f;
}

// K9: w2t[n][co][f] = w2[f][co]*a[n][f]  (bf16)
__global__ __launch_bounds__(512) void k_w2prep(
    const float* __restrict__ w2, const float* __restrict__ aBuf, ush* __restrict__ w2t)
{
  const int n = blockIdx.x, tid = threadIdx.x;
  for (int i = tid; i < 128*512; i += 512) {
    int f = i >> 7, co = i & 127;
    w2t[((size_t)n*128 + co)*512 + f] = f2bf(w2[(size_t)f*128 + co] * aBuf[n*512 + f]);
  }
}

// K10: cvec[co] = grn_b @ w2
__global__ void k_cvec(const float* __restrict__ w2, const float* __restrict__ grn_b,
                       float* __restrict__ cvec)
{
  const int co = threadIdx.x;
  float s = 0.f;
  for (int f = 0; f < 512; f++) s += grn_b[f]*w2[f*128 + co];
  cvec[co] = s;
}

// ---------------------------------------------------------------------------
// K11: GEMM2  u[n,s,c] = t @ w2t_n^T + cvec, bf16 out + post-BN partials
// tile 128m x 128c, K=512 in 4 steps
// ---------------------------------------------------------------------------
__global__ __launch_bounds__(256) void k_gemm2(
    const ush* __restrict__ tbuf, const ush* __restrict__ w2t,
    const float* __restrict__ cvec, ush* __restrict__ u, float* __restrict__ upart)
{
  __shared__ __align__(16) ush Al[16384];
  __shared__ __align__(16) ush Bl[16384];
  const int mt = blockIdx.x, n = blockIdx.y, tid = threadIdx.x;
  const int wid = tid >> 6, lane = tid & 63;
  const int wm = wid >> 1, wn = wid & 1;
  const int lr = lane & 15, lk = lane >> 4;
  f32x4 acc[4][4] = {};
  #pragma unroll 1
  for (int kb = 0; kb < 4; kb++) {
    if (kb) __syncthreads();
    #pragma unroll
    for (int i = 0; i < 8; i++) {
      int g = i*256 + tid;
      int r = g >> 4, cg = g & 15;
      *(uint4*)&Al[r*128 + ((cg ^ (r & 7))*8)] =
        *(const uint4*)(tbuf + ((size_t)n*CS + (size_t)mt*128 + r)*512 + kb*128 + cg*8);
      *(uint4*)&Bl[r*128 + ((cg ^ (r & 7))*8)] =
        *(const uint4*)(w2t + ((size_t)n*128 + r)*512 + kb*128 + cg*8);
    }
    __syncthreads();
    #pragma unroll
    for (int kk = 0; kk < 4; kk++) {
      short8 af[4], bfr[4];
      #pragma unroll
      for (int mf = 0; mf < 4; mf++) {
        int row = wm*64 + mf*16 + lr;
        int cg = (kk*4 + lk) ^ (row & 7);
        af[mf] = *(const short8*)&Al[row*128 + cg*8];
      }
      #pragma unroll
      for (int nf = 0; nf < 4; nf++) {
        int row = wn*64 + nf*16 + lr;
        int cg = (kk*4 + lk) ^ (row & 7);
        bfr[nf] = *(const short8*)&Bl[row*128 + cg*8];
      }
      #pragma unroll
      for (int mf = 0; mf < 4; mf++)
        #pragma unroll
        for (int nf = 0; nf < 4; nf++)
          acc[mf][nf] = __builtin_amdgcn_mfma_f32_16x16x32_bf16(af[mf], bfr[nf], acc[mf][nf], 0, 0, 0);
    }
  }
  float cv[4];
  #pragma unroll
  for (int nf = 0; nf < 4; nf++) cv[nf] = cvec[wn*64 + nf*16 + lr];
  float su[4] = {0,0,0,0}, sq[4] = {0,0,0,0};
  #pragma unroll
  for (int mf = 0; mf < 4; mf++)
    #pragma unroll
    for (int nf = 0; nf < 4; nf++)
      #pragma unroll
      for (int r = 0; r < 4; r++) {
        float v = acc[mf][nf][r] + cv[nf];
        su[nf] += v; sq[nf] += v*v;
        acc[mf][nf][r] = v;
      }
  __syncthreads();
  float* stl = (float*)Al;                  // [128][2 wm][2]
  #pragma unroll
  for (int nf = 0; nf < 4; nf++) {
    float a = su[nf]; a += __shfl_xor(a, 16); a += __shfl_xor(a, 32);
    float b = sq[nf]; b += __shfl_xor(b, 16); b += __shfl_xor(b, 32);
    if (lane < 16) {
      stl[((wn*64 + nf*16 + lane)*2 + wm)*2 + 0] = a;
      stl[((wn*64 + nf*16 + lane)*2 + wm)*2 + 1] = b;
    }
  }
  #pragma unroll
  for (int mf = 0; mf < 4; mf++)
    #pragma unroll
    for (int nf = 0; nf < 4; nf++)
      #pragma unroll
      for (int r = 0; r < 4; r++) {
        int ml = wm*64 + mf*16 + lk*4 + r;
        int fl = wn*64 + nf*16 + lr;
        Bl[ml*128 + (fl ^ (((ml >> 2) & 3) << 4))] = f2bf(acc[mf][nf][r]);
      }
  __syncthreads();
  #pragma unroll
  for (int i = 0; i < 8; i++) {
    int idx = i*256 + tid;
    int m = idx >> 4, gc = idx & 15;
    uint4 v = *(const uint4*)&Bl[m*128 + ((gc ^ (((m >> 2) & 3) << 1))*8)];
    *(uint4*)(u + ((size_t)n*CS + (size_t)mt*128 + m)*128 + gc*8) = v;
  }
  if (tid < 128) {
    float s = stl[(tid*2 + 0)*2 + 0] + stl[(tid*2 + 1)*2 + 0];
    float q = stl[(tid*2 + 0)*2 + 1] + stl[(tid*2 + 1)*2 + 1];
    upart[((size_t)(n*1024 + mt)*128 + tid)*2 + 0] = s;
    upart[((size_t)(n*1024 + mt)*128 + tid)*2 + 1] = q;
  }
}

// K12: post-BN stats -> P,Q per channel
__global__ __launch_bounds__(256) void k_pbn(
    const float* __restrict__ upart, const float* pbn_w, const float* pbn_b,
    const float* ls_g, float* __restrict__ PQ)
{
  __shared__ float rs[4], rq[4];
  const int c = blockIdx.x, tid = threadIdx.x;
  float s = 0.f, q = 0.f;
  for (int mtg = tid; mtg < 2048; mtg += 256) {
    s += upart[((size_t)mtg*128 + c)*2 + 0];
    q += upart[((size_t)mtg*128 + c)*2 + 1];
  }
  s = wave_sum(s); q = wave_sum(q);
  if ((tid & 63) == 0) { rs[tid >> 6] = s; rq[tid >> 6] = q; }
  __syncthreads();
  if (tid == 0) {
    float S = rs[0]+rs[1]+rs[2]+rs[3];
    float Qq = rq[0]+rq[1]+rq[2]+rq[3];
    float m = S*(1.f/262144.f);
    float var = Qq*(1.f/262144.f) - m*m;
    float inv = rsqrtf(var + BNEPS);
    PQ[c*2 + 0] = ls_g[c]*pbn_w[c]*inv;
    PQ[c*2 + 1] = ls_g[c]*(pbn_b[c] - m*inv*pbn_w[c]);
  }
}

// K13: out[n,c,s] = x + u[n,s,c]*P[c] + Q[c]   (LDS transpose back)
__global__ __launch_bounds__(256) void k_final(
    const ush* __restrict__ u, const float* __restrict__ x,
    const float* __restrict__ PQ, float* __restrict__ out)
{
  __shared__ ush ld[32768];
  __shared__ float Ps[128], Qs[128];
  const int sblk = blockIdx.x, n = blockIdx.y, tid = threadIdx.x;
  if (tid < 128) { Ps[tid] = PQ[tid*2]; Qs[tid] = PQ[tid*2 + 1]; }
  #pragma unroll 2
  for (int i = 0; i < 16; i++) {
    int idx = i*256 + tid;
    int s_l = idx >> 4, gc = idx & 15;
    *(uint4*)&ld[idx*8] = *(const uint4*)(u + ((size_t)n*CS + sblk*256 + s_l)*128 + gc*8);
  }
  __syncthreads();
  const int c = tid >> 1, sh = tid & 1;
  const float P = Ps[c], Q = Qs[c];
  const float* xp = x + ((size_t)(n*CC + c))*CS + sblk*256 + sh*128;
  float* op = out + ((size_t)(n*CC + c))*CS + sblk*256 + sh*128;
  #pragma unroll 4
  for (int j4 = 0; j4 < 32; j4++) {
    float4 xv = *(const float4*)(xp + j4*4);
    int s0 = sh*128 + j4*4;
    float4 ov;
    ov.x = xv.x + bf2f(ld[(s0+0)*128 + c])*P + Q;
    ov.y = xv.y + bf2f(ld[(s0+1)*128 + c])*P + Q;
    ov.z = xv.z + bf2f(ld[(s0+2)*128 + c])*P + Q;
    ov.w = xv.w + bf2f(ld[(s0+3)*128 + c])*P + Q;
    *(float4*)(op + j4*4) = ov;
  }
}

// ---------------------------------------------------------------------------
extern "C" void kernel_launch(void* const* d_in, const int* in_sizes, int n_in,
                              void* d_out, int out_size, void* d_ws, size_t ws_size,
                              hipStream_t stream)
{
  (void)in_sizes; (void)n_in; (void)out_size; (void)ws_size;
  const float* x      = (const float*)d_in[0];
  const float* lk_w   = (const float*)d_in[1];
  const float* bn0_w  = (const float*)d_in[2];
  const float* bn0_b  = (const float*)d_in[3];
  const float* dw5_w  = (const float*)d_in[4];
  const float* dbn1_w = (const float*)d_in[5];
  const float* dbn1_b = (const float*)d_in[6];
  const float* dw3a_w = (const float*)d_in[7];
  const float* dbn2_w = (const float*)d_in[8];
  const float* dbn2_b = (const float*)d_in[9];
  const float* dw3b_w = (const float*)d_in[10];
  const float* dbn3_w = (const float*)d_in[11];
  const float* dbn3_b = (const float*)d_in[12];
  const float* nrm_w  = (const float*)d_in[13];
  const float* nrm_b  = (const float*)d_in[14];
  const float* se_dw  = (const float*)d_in[15];
  const float* se_db  = (const float*)d_in[16];
  const float* se_uw  = (const float*)d_in[17];
  const float* se_ub  = (const float*)d_in[18];
  const float* w1     = (const float*)d_in[19];
  const float* b1     = (const float*)d_in[20];
  const float* grn_g  = (const float*)d_in[21];
  const float* grn_b  = (const float*)d_in[22];
  const float* w2     = (const float*)d_in[23];
  const float* pbn_w  = (const float*)d_in[24];
  const float* pbn_b  = (const float*)d_in[25];
  const float* ls_g   = (const float*)d_in[26];

  // workspace layout (~343 MB total)
  char* w = (char*)d_ws;
  size_t cur = 0;
  auto take = [&](size_t b) { size_t r = cur; cur += (b + 255) & ~(size_t)255; return r; };
  ush*   y_pre = (ush*)  (w + take((size_t)2*CC*CS*2));   // 67MB, reused as u
  float* part1 = (float*)(w + take(4096*8*4));
  float* part2 = (float*)(w + take(4096*2*4));
  float* coef3 = (float*)(w + take(128*49*4*4));
  float* Tbuf  = (float*)(w + take(128*4));
  float* ABuf  = (float*)(w + take(2*128*2*4));
  ush*   w1t   = (ush*)  (w + take(2*512*128*2));
  float* beta  = (float*)(w + take(2*512*4));
  float* grnp  = (float*)(w + take((size_t)1024*1024*4));
  float* aBuf  = (float*)(w + take(2*512*4));
  ush*   w2t   = (ush*)  (w + take(2*128*512*2));
  float* cvec  = (float*)(w + take(128*4));
  float* upart = (float*)(w + take((size_t)2048*128*2*4));
  float* PQ    = (float*)(w + take(128*2*4));
  ush*   tbuf  = (ush*)  (w + take((size_t)2*CS*512*2)); // 268MB
  ush*   u_buf = y_pre;                                  // reuse (y_pre dead after transpose)
  ush*   y_cl  = (ush*)d_out;                            // scratch in d_out (67MB < 134MB), dead before k_final
  float* outp  = (float*)d_out;

  k_conv_stats<<<dim3(16,128,2), 512, 0, stream>>>(x, lk_w, dw5_w, dw3a_w, dw3b_w, part1);
  k_branch_reduce<<<1, 512, 0, stream>>>(part1, bn0_w, bn0_b, dbn1_w, dbn1_b,
                                         dbn2_w, dbn2_b, dbn3_w, dbn3_b,
                                         lk_w, dw5_w, dw3a_w, dw3b_w, coef3, Tbuf);
  k_conv_main<<<dim3(16,128,2), 512, 0, stream>>>(x, coef3, Tbuf, y_pre, part2);
  k_bn_se<<<1, 256, 0, stream>>>(part2, nrm_w, nrm_b, se_dw, se_db, se_uw, se_ub, ABuf);
  k_w1prep<<<2, 512, 0, stream>>>(w1, b1, ABuf, w1t, beta);
  k_transpose<<<dim3(512,2), 256, 0, stream>>>(y_pre, y_cl);
  k_gemm1<<<dim3(1024,4,2), 256, 0, stream>>>(y_cl, w1t, beta, tbuf, grnp);
  k_grn<<<1, 1024, 0, stream>>>(grnp, grn_g, aBuf);
  k_w2prep<<<2, 512, 0, stream>>>(w2, aBuf, w2t);
  k_cvec<<<1, 128, 0, stream>>>(w2, grn_b, cvec);
  k_gemm2<<<dim3(1024,2), 256, 0, stream>>>(tbuf, w2t, cvec, u_buf, upart);
  k_pbn<<<128, 256, 0, stream>>>(upart, pbn_w, pbn_b, ls_g, PQ);
  k_final<<<dim3(512,2), 256, 0, stream>>>(u_buf, x, PQ, outp);
}

// Round 2
// 1461.399 us; speedup vs baseline: 1.4034x; 1.4034x over previous
//
#include <hip/hip_runtime.h>
#include <stdint.h>

typedef unsigned short ush;
typedef unsigned int u32;
typedef __attribute__((ext_vector_type(8))) short short8;
typedef __attribute__((ext_vector_type(4))) float f32x4;

#define DEVI static __device__ __forceinline__

constexpr int CC = 128, CH = 128;
constexpr int CS = 131072;           // H*W*Z per (n,c)
constexpr float BNEPS = 1e-5f;

DEVI ush f2bf(float f) {
  u32 u = __float_as_uint(f);
  u += 0x7FFF + ((u >> 16) & 1);     // RNE
  return (ush)(u >> 16);
}
DEVI float bf2f(ush h) { return __uint_as_float(((u32)h) << 16); }

DEVI float gelu_tanh(float v) {
  float y = 0.79788456f * (v + 0.044715f * v * v * v);
  float e = __expf(2.0f * y);
  return v * (1.0f - 1.0f / (e + 1.0f));
}

DEVI float wave_sum(float v) {
  v += __shfl_xor(v, 1);  v += __shfl_xor(v, 2);  v += __shfl_xor(v, 4);
  v += __shfl_xor(v, 8);  v += __shfl_xor(v, 16); v += __shfl_xor(v, 32);
  return v;
}

// ---------------------------------------------------------------------------
// Shared staging: x (n,c,h,w,z) tile -> sm[row][z][w], 14 rows, phys w = 4+w
// block 256 thr, covers 8 output h-rows (hb), one (c,n).
// ---------------------------------------------------------------------------
DEVI void stage_tile(const float* __restrict__ xc, float* sm, int hb, int tid) {
  #pragma unroll
  for (int i = 0; i < 14; ++i) {
    int idx = i*256 + tid;               // 3584 = 14 rows * 256 float4
    int row = idx >> 8, r4 = idx & 255;
    int w = r4 >> 1, zh = r4 & 1;
    int hin = hb*8 - 3 + row;
    float4 val = make_float4(0.f,0.f,0.f,0.f);
    if (hin >= 0 && hin < CH) val = *(const float4*)(xc + (size_t)hin*1024 + w*8 + zh*4);
    float* base = sm + (row*8 + zh*4)*136 + 4 + w;
    base[0] = val.x; base[136] = val.y; base[272] = val.z; base[408] = val.w;
  }
  // zero the w-halo (logical w in [-4,-1] and [128,131])
  for (int idx = tid; idx < 896; idx += 256) {
    int row = idx >> 6, rem = idx & 63;
    int z = rem >> 3, col = rem & 7;
    int pw = (col < 4) ? col : (124 + col);   // 0..3 and 128..131 phys? col4..7 -> 128..131
    sm[(row*8 + z)*136 + pw] = 0.f;
  }
}

#define ACC3(ACC, C0, C1, C2, XV)                                   \
  do {                                                              \
    if (zi > 0) ACC[zi-1][wp] = fmaf((C2), (XV), ACC[zi-1][wp]);    \
    ACC[zi][wp]   = fmaf((C1), (XV), ACC[zi][wp]);                  \
    if (zi < 7) ACC[zi+1][wp] = fmaf((C0), (XV), ACC[zi+1][wp]);    \
  } while (0)

// ---------------------------------------------------------------------------
// K1: 4-branch depthwise conv, stats only. block 256 = 32 wt (x4 w) x 8 hh
// ---------------------------------------------------------------------------
__global__ __launch_bounds__(256) void k_conv_stats(
    const float* __restrict__ x, const float* __restrict__ lk_w,
    const float* __restrict__ dw5_w, const float* __restrict__ dw3a_w,
    const float* __restrict__ dw3b_w, float* __restrict__ part1)
{
  __shared__ float sm[14*8*136];
  __shared__ float red[4][8];
  const int hb = blockIdx.x, c = blockIdx.y, n = blockIdx.z, tid = threadIdx.x;
  const float* xc = x + ((size_t)(n*CC + c)) * CS;
  stage_tile(xc, sm, hb, tid);
  __syncthreads();

  const int wt = tid & 31, hh = tid >> 5;
  float a0[8][4] = {}, a1[8][4] = {}, a2[8][4] = {}, a3[8][4] = {};
  const float* lkc = lk_w  + c*147;
  const float* w5c = dw5_w + c*75;
  const float* w3a = dw3a_w + c*27;
  const float* w3b = dw3b_w + c*27;

  #pragma unroll 1
  for (int dh = 0; dh < 7; ++dh) {
    const float* smr = sm + (size_t)((hh + dh)*8)*136 + 4*wt;
    const bool b1on = (dh >= 1 && dh <= 5);
    const bool b2on = (dh & 1) != 0;
    const bool b3on = (dh == 0 || dh == 3 || dh == 6);
    #pragma unroll
    for (int zi = 0; zi < 8; ++zi) {
      float4 vA = *(const float4*)(smr + zi*136);
      float4 vB = *(const float4*)(smr + zi*136 + 4);
      float4 vC = *(const float4*)(smr + zi*136 + 8);
      float v[12] = {vA.x,vA.y,vA.z,vA.w, vB.x,vB.y,vB.z,vB.w, vC.x,vC.y,vC.z,vC.w};
      #pragma unroll
      for (int dwi = 0; dwi < 7; ++dwi) {
        const float* cp = lkc + (dh*7 + dwi)*3;
        float c0 = cp[0], c1 = cp[1], c2 = cp[2];
        #pragma unroll
        for (int wp = 0; wp < 4; ++wp) {
          float xv = v[1 + wp + dwi];
          ACC3(a0, c0, c1, c2, xv);
        }
      }
      if (b1on) {
        #pragma unroll
        for (int dwi = 1; dwi <= 5; ++dwi) {
          const float* cp = w5c + ((dh-1)*5 + (dwi-1))*3;
          float c0 = cp[0], c1 = cp[1], c2 = cp[2];
          #pragma unroll
          for (int wp = 0; wp < 4; ++wp) {
            float xv = v[1 + wp + dwi];
            ACC3(a1, c0, c1, c2, xv);
          }
        }
      }
      if (b2on) {
        #pragma unroll
        for (int k = 0; k < 3; ++k) {
          const int dwi = 1 + 2*k;
          const float* cp = w3a + (((dh-1)>>1)*3 + k)*3;
          float c0 = cp[0], c1 = cp[1], c2 = cp[2];
          #pragma unroll
          for (int wp = 0; wp < 4; ++wp) {
            float xv = v[1 + wp + dwi];
            ACC3(a2, c0, c1, c2, xv);
          }
        }
      }
      if (b3on) {
        #pragma unroll
        for (int k = 0; k < 3; ++k) {
          const int dwi = 3*k;
          const float* cp = w3b + ((dh/3)*3 + k)*3;
          float c0 = cp[0], c1 = cp[1], c2 = cp[2];
          #pragma unroll
          for (int wp = 0; wp < 4; ++wp) {
            float xv = v[1 + wp + dwi];
            ACC3(a3, c0, c1, c2, xv);
          }
        }
      }
    }
  }

  float s0=0,q0=0,s1=0,q1=0,s2=0,q2=0,s3=0,q3=0;
  #pragma unroll
  for (int z = 0; z < 8; ++z)
    #pragma unroll
    for (int wp = 0; wp < 4; ++wp) {
      s0 += a0[z][wp]; q0 = fmaf(a0[z][wp], a0[z][wp], q0);
      s1 += a1[z][wp]; q1 = fmaf(a1[z][wp], a1[z][wp], q1);
      s2 += a2[z][wp]; q2 = fmaf(a2[z][wp], a2[z][wp], q2);
      s3 += a3[z][wp]; q3 = fmaf(a3[z][wp], a3[z][wp], q3);
    }
  float vals[8] = {s0,s1,s2,s3,q0,q1,q2,q3};
  #pragma unroll
  for (int j = 0; j < 8; ++j) vals[j] = wave_sum(vals[j]);
  const int wid = tid >> 6, lane = tid & 63;
  if (lane == 0) {
    #pragma unroll
    for (int j = 0; j < 8; ++j) red[wid][j] = vals[j];
  }
  __syncthreads();
  if (tid < 8) {
    float s = red[0][tid] + red[1][tid] + red[2][tid] + red[3][tid];
    part1[(((size_t)n*CC + c)*16 + hb)*8 + tid] = s;
  }
}

// ---------------------------------------------------------------------------
// K2: reduce branch stats -> BN affines -> combined 7x7x3 kernel + constant T
// ---------------------------------------------------------------------------
__global__ __launch_bounds__(512) void k_branch_reduce(
    const float* __restrict__ part1,
    const float* bn0_w, const float* bn0_b, const float* dbn1_w, const float* dbn1_b,
    const float* dbn2_w, const float* dbn2_b, const float* dbn3_w, const float* dbn3_b,
    const float* lk_w, const float* dw5_w, const float* dw3a_w, const float* dw3b_w,
    float* __restrict__ coef3, float* __restrict__ Tbuf)
{
  __shared__ float sA[4][128], tA[4][128];
  const int tid = threadIdx.x;
  {
    int c = tid >> 2, b = tid & 3;
    float s = 0.f, q = 0.f;
    for (int n = 0; n < 2; n++)
      for (int hb = 0; hb < 16; hb++) {
        const float* p = part1 + (((size_t)n*CC + c)*16 + hb)*8;
        s += p[b]; q += p[4 + b];
      }
    float mean = s * (1.f/262144.f);
    float var  = q * (1.f/262144.f) - mean*mean;
    float g, bb;
    if (b == 0)      { g = bn0_w[c];  bb = bn0_b[c];  }
    else if (b == 1) { g = dbn1_w[c]; bb = dbn1_b[c]; }
    else if (b == 2) { g = dbn2_w[c]; bb = dbn2_b[c]; }
    else             { g = dbn3_w[c]; bb = dbn3_b[c]; }
    float sc = g * rsqrtf(var + BNEPS);
    sA[b][c] = sc;
    tA[b][c] = bb - mean * sc;
  }
  __syncthreads();
  for (int i = tid; i < 128*49; i += 512) {
    int c = i / 49, tap = i % 49;
    int dh = tap / 7, dw = tap % 7;
    float s0 = sA[0][c], s1 = sA[1][c], s2 = sA[2][c], s3 = sA[3][c];
    float kz[3];
    #pragma unroll
    for (int dz = 0; dz < 3; dz++) {
      float v = s0 * lk_w[c*147 + dh*21 + dw*3 + dz];
      if (dh>=1 && dh<=5 && dw>=1 && dw<=5) v += s1 * dw5_w[c*75 + (dh-1)*15 + (dw-1)*3 + dz];
      if ((dh&1) && (dw&1))                 v += s2 * dw3a_w[c*27 + ((dh-1)>>1)*9 + ((dw-1)>>1)*3 + dz];
      if (dh%3==0 && dw%3==0)               v += s3 * dw3b_w[c*27 + (dh/3)*9 + (dw/3)*3 + dz];
      kz[dz] = v;
    }
    *(float4*)(coef3 + (size_t)i*4) = make_float4(kz[0], kz[1], kz[2], 0.f);
  }
  if (tid < 128) Tbuf[tid] = tA[0][tid] + tA[1][tid] + tA[2][tid] + tA[3][tid];
}

// ---------------------------------------------------------------------------
// K3: combined 147-tap conv -> y_pre (bf16, NCS layout) + block-BN/SE partials
// ---------------------------------------------------------------------------
__global__ __launch_bounds__(256) void k_conv_main(
    const float* __restrict__ x, const float* __restrict__ coef3,
    const float* __restrict__ Tbuf, ush* __restrict__ y_pre, float* __restrict__ part2)
{
  __shared__ float sm[14*8*136];
  __shared__ float red2[4][2];
  const int hb = blockIdx.x, c = blockIdx.y, n = blockIdx.z, tid = threadIdx.x;
  const float* xc = x + ((size_t)(n*CC + c)) * CS;
  stage_tile(xc, sm, hb, tid);
  __syncthreads();

  const int wt = tid & 31, hh = tid >> 5;
  const float Tc = Tbuf[c];
  float a[8][4] = {};
  const float* cfc = coef3 + (size_t)c*49*4;

  #pragma unroll 1
  for (int dh = 0; dh < 7; ++dh) {
    const float* smr = sm + (size_t)((hh + dh)*8)*136 + 4*wt;
    #pragma unroll
    for (int zi = 0; zi < 8; ++zi) {
      float4 vA = *(const float4*)(smr + zi*136);
      float4 vB = *(const float4*)(smr + zi*136 + 4);
      float4 vC = *(const float4*)(smr + zi*136 + 8);
      float v[12] = {vA.x,vA.y,vA.z,vA.w, vB.x,vB.y,vB.z,vB.w, vC.x,vC.y,vC.z,vC.w};
      #pragma unroll
      for (int dwi = 0; dwi < 7; ++dwi) {
        const float* cp = cfc + (dh*7 + dwi)*4;
        float c0 = cp[0], c1 = cp[1], c2 = cp[2];
        #pragma unroll
        for (int wp = 0; wp < 4; ++wp) {
          float xv = v[1 + wp + dwi];
          ACC3(a, c0, c1, c2, xv);
        }
      }
    }
  }

  const int ho = hb*8 + hh;
  float ssum = 0.f, ssq = 0.f;
  ush* yp = y_pre + ((size_t)(n*CC + c))*CS + (size_t)ho*1024 + wt*32;
  #pragma unroll
  for (int wp = 0; wp < 4; ++wp) {
    ush o8[8];
    #pragma unroll
    for (int z = 0; z < 8; ++z) {
      float yv = a[z][wp] + Tc;
      ssum += yv; ssq = fmaf(yv, yv, ssq);
      o8[z] = f2bf(yv);
    }
    u32 p0 = (u32)o8[0] | ((u32)o8[1] << 16);
    u32 p1 = (u32)o8[2] | ((u32)o8[3] << 16);
    u32 p2 = (u32)o8[4] | ((u32)o8[5] << 16);
    u32 p3 = (u32)o8[6] | ((u32)o8[7] << 16);
    *(uint4*)(yp + wp*8) = make_uint4(p0,p1,p2,p3);
  }
  float vs = wave_sum(ssum), vq = wave_sum(ssq);
  const int wid = tid >> 6, lane = tid & 63;
  if (lane == 0) { red2[wid][0] = vs; red2[wid][1] = vq; }
  __syncthreads();
  if (tid < 2) {
    float s = red2[0][tid] + red2[1][tid] + red2[2][tid] + red2[3][tid];
    part2[(((size_t)n*CC + c)*16 + hb)*2 + tid] = s;
  }
}

// ---------------------------------------------------------------------------
// K4: block-BN stats + SE -> per-(n,c) affine A,B for GEMM1 input folding
// ---------------------------------------------------------------------------
__global__ __launch_bounds__(256) void k_bn_se(
    const float* __restrict__ part2, const float* nrm_w, const float* nrm_b,
    const float* se_dw, const float* se_db, const float* se_uw, const float* se_ub,
    float* __restrict__ ABuf)
{
  __shared__ float pmA[2][128], hA[2][32], alA[128], beA[128];
  const int tid = threadIdx.x;
  if (tid < 128) {
    int c = tid;
    float s=0.f, q=0.f, p0=0.f, p1=0.f;
    for (int n = 0; n < 2; n++)
      for (int hb = 0; hb < 16; hb++) {
        float v = part2[(((size_t)n*CC + c)*16 + hb)*2];
        s += v; q += part2[(((size_t)n*CC + c)*16 + hb)*2 + 1];
        if (n == 0) p0 += v; else p1 += v;
      }
    float m   = s * (1.f/262144.f);
    float var = q * (1.f/262144.f) - m*m;
    float inv = rsqrtf(var + BNEPS);
    float al = nrm_w[c]*inv;
    float be = nrm_b[c] - m*al;
    alA[c] = al; beA[c] = be;
    pmA[0][c] = (p0*(1.f/131072.f) - m)*al + be;
    pmA[1][c] = (p1*(1.f/131072.f) - m)*al + be;
  }
  __syncthreads();
  if (tid < 64) {
    int n = tid >> 5, i = tid & 31;
    float h = se_db[i];
    for (int c2 = 0; c2 < 128; c2++) h += pmA[n][c2]*se_dw[i*128 + c2];
    hA[n][i] = fmaxf(h, 0.f);
  }
  __syncthreads();
  {
    int n = tid >> 7, c = tid & 127;
    float sse = se_ub[c];
    #pragma unroll
    for (int i = 0; i < 32; i++) sse += hA[n][i]*se_uw[c*32 + i];
    ABuf[(n*128 + c)*2 + 0] = alA[c]*sse;
    ABuf[(n*128 + c)*2 + 1] = beA[c]*sse;
  }
}

// ---------------------------------------------------------------------------
// K5: fold A into w1 (bf16, [n][f][c]) and B into beta[n][f]
// ---------------------------------------------------------------------------
__global__ __launch_bounds__(512) void k_w1prep(
    const float* __restrict__ w1, const float* __restrict__ b1,
    const float* __restrict__ ABuf, ush* __restrict__ w1t, float* __restrict__ beta)
{
  const int n = blockIdx.x, tid = threadIdx.x;
  __shared__ float Asc[128], Bsc[128];
  if (tid < 128) { Asc[tid] = ABuf[(n*128 + tid)*2]; Bsc[tid] = ABuf[(n*128 + tid)*2 + 1]; }
  __syncthreads();
  for (int i = tid; i < 512*128; i += 512) {
    int cc = i >> 9, f = i & 511;
    w1t[((size_t)n*512 + f)*128 + cc] = f2bf(w1[cc*512 + f] * Asc[cc]);
  }
  {
    int f = tid;
    float s = b1[f];
    for (int cc = 0; cc < 128; cc++) s += Bsc[cc]*w1[cc*512 + f];
    beta[n*512 + f] = s;
  }
}

// ---------------------------------------------------------------------------
// K6: transpose y_pre (n,c,s) -> y_cl (n,s,c), both bf16
// ---------------------------------------------------------------------------
__global__ __launch_bounds__(256) void k_transpose(
    const ush* __restrict__ y_pre, ush* __restrict__ y_cl)
{
  __shared__ ush ld[32768];
  const int sblk = blockIdx.x, n = blockIdx.y, tid = threadIdx.x;
  #pragma unroll 2
  for (int i = 0; i < 16; i++) {
    int idx = i*256 + tid;
    int c = idx >> 5, gs = idx & 31;
    uint4 v = *(const uint4*)(y_pre + ((size_t)(n*CC + c))*CS + sblk*256 + gs*8);
    union { uint4 q; ush e[8]; } uu; uu.q = v;
    #pragma unroll
    for (int j = 0; j < 8; j++) {
      int s_l = gs*8 + j;
      int gran = s_l*16 + ((c >> 3) ^ (gs & 7));
      ld[gran*8 + (c & 7)] = uu.e[j];
    }
  }
  __syncthreads();
  #pragma unroll 2
  for (int i = 0; i < 16; i++) {
    int idx = i*256 + tid;
    int s_l = idx >> 4, gc = idx & 15;
    int gran = s_l*16 + (gc ^ ((s_l >> 3) & 7));
    uint4 v = *(const uint4*)&ld[gran*8];
    *(uint4*)(y_cl + ((size_t)n*CS + sblk*256 + s_l)*128 + gc*8) = v;
  }
}

// ---------------------------------------------------------------------------
// K7: GEMM1  t[n,s,f] = gelu( y_cl @ w1t_n^T + beta ), bf16 out + GRN partials
// ---------------------------------------------------------------------------
__global__ __launch_bounds__(256) void k_gemm1(
    const ush* __restrict__ y_cl, const ush* __restrict__ w1t,
    const float* __restrict__ beta, ush* __restrict__ tbuf, float* __restrict__ grnp)
{
  __shared__ __align__(16) ush Al[16384];
  __shared__ __align__(16) ush Bl[16384];
  const int mt = blockIdx.x, ft = blockIdx.y, n = blockIdx.z, tid = threadIdx.x;
  const ush* Ab = y_cl + ((size_t)n*CS + (size_t)mt*128) * 128;
  const ush* Bb = w1t + ((size_t)n*512 + (size_t)ft*128) * 128;
  #pragma unroll
  for (int i = 0; i < 8; i++) {
    int g = i*256 + tid;
    int r = g >> 4, cg = g & 15;
    *(uint4*)&Al[r*128 + ((cg ^ (r & 7))*8)] = *(const uint4*)(Ab + (size_t)g*8);
    *(uint4*)&Bl[r*128 + ((cg ^ (r & 7))*8)] = *(const uint4*)(Bb + (size_t)g*8);
  }
  __syncthreads();

  const int wid = tid >> 6, lane = tid & 63;
  const int wm = wid >> 1, wn = wid & 1;
  const int lr = lane & 15, lk = lane >> 4;
  f32x4 acc[4][4] = {};
  #pragma unroll
  for (int kk = 0; kk < 4; kk++) {
    short8 af[4], bfr[4];
    #pragma unroll
    for (int mf = 0; mf < 4; mf++) {
      int row = wm*64 + mf*16 + lr;
      int cg = (kk*4 + lk) ^ (row & 7);
      af[mf] = *(const short8*)&Al[row*128 + cg*8];
    }
    #pragma unroll
    for (int nf = 0; nf < 4; nf++) {
      int row = wn*64 + nf*16 + lr;
      int cg = (kk*4 + lk) ^ (row & 7);
      bfr[nf] = *(const short8*)&Bl[row*128 + cg*8];
    }
    #pragma unroll
    for (int mf = 0; mf < 4; mf++)
      #pragma unroll
      for (int nf = 0; nf < 4; nf++)
        acc[mf][nf] = __builtin_amdgcn_mfma_f32_16x16x32_bf16(af[mf], bfr[nf], acc[mf][nf], 0, 0, 0);
  }

  float bt[4];
  #pragma unroll
  for (int nf = 0; nf < 4; nf++) bt[nf] = beta[n*512 + ft*128 + wn*64 + nf*16 + lr];
  float sq[4] = {0.f,0.f,0.f,0.f};
  #pragma unroll
  for (int mf = 0; mf < 4; mf++)
    #pragma unroll
    for (int nf = 0; nf < 4; nf++)
      #pragma unroll
      for (int r = 0; r < 4; r++) {
        float g = gelu_tanh(acc[mf][nf][r] + bt[nf]);
        sq[nf] += g*g;
        acc[mf][nf][r] = g;
      }
  __syncthreads();
  float* grnl = (float*)Al;
  #pragma unroll
  for (int nf = 0; nf < 4; nf++) {
    float v = sq[nf];
    v += __shfl_xor(v, 16); v += __shfl_xor(v, 32);
    if (lane < 16) grnl[(wn*64 + nf*16 + lane)*2 + wm] = v;
  }
  #pragma unroll
  for (int mf = 0; mf < 4; mf++)
    #pragma unroll
    for (int nf = 0; nf < 4; nf++)
      #pragma unroll
      for (int r = 0; r < 4; r++) {
        int ml = wm*64 + mf*16 + lk*4 + r;
        int fl = wn*64 + nf*16 + lr;
        Bl[ml*128 + (fl ^ (((ml >> 2) & 3) << 4))] = f2bf(acc[mf][nf][r]);
      }
  __syncthreads();
  #pragma unroll
  for (int i = 0; i < 8; i++) {
    int idx = i*256 + tid;
    int m = idx >> 4, gc = idx & 15;
    uint4 v = *(const uint4*)&Bl[m*128 + ((gc ^ (((m >> 2) & 3) << 1))*8)];
    *(uint4*)(tbuf + ((size_t)n*CS + (size_t)mt*128 + m)*512 + ft*128 + gc*8) = v;
  }
  if (tid < 128) grnp[(size_t)mt*1024 + n*512 + ft*128 + tid] = grnl[tid*2] + grnl[tid*2+1];
}

// ---------------------------------------------------------------------------
// K8: GRN: Gx -> Nx -> a[n][f] = grn_g*Nx + 1
// ---------------------------------------------------------------------------
__global__ __launch_bounds__(1024) void k_grn(
    const float* __restrict__ grnp, const float* __restrict__ grn_g, float* __restrict__ aBuf)
{
  __shared__ float wsum[16], gm[2];
  const int tid = threadIdx.x;
  float s = 0.f;
  for (int mtv = 0; mtv < 1024; mtv++) s += grnp[(size_t)mtv*1024 + tid];
  float Gx = sqrtf(s);
  float v = wave_sum(Gx);
  if ((tid & 63) == 0) wsum[tid >> 6] = v;
  __syncthreads();
  if (tid < 2) {
    float m = 0.f;
    #pragma unroll
    for (int w2 = 0; w2 < 8; w2++) m += wsum[tid*8 + w2];
    gm[tid] = m * (1.f/512.f) + 1e-6f;
  }
  __syncthreads();
  int n = tid >> 9, f = tid & 511;
  aBuf[tid] = grn_g[f] * (Gx / gm[n]) + 1.f;
}

// K9: w2t[n][co][f] = w2[f][co]*a[n][f]  (bf16)
__global__ __launch_bounds__(512) void k_w2prep(
    const float* __restrict__ w2, const float* __restrict__ aBuf, ush* __restrict__ w2t)
{
  const int n = blockIdx.x, tid = threadIdx.x;
  for (int i = tid; i < 128*512; i += 512) {
    int f = i >> 7, co = i & 127;
    w2t[((size_t)n*128 + co)*512 + f] = f2bf(w2[(size_t)f*128 + co] * aBuf[n*512 + f]);
  }
}

// K10: cvec[co] = grn_b @ w2
__global__ void k_cvec(const float* __restrict__ w2, const float* __restrict__ grn_b,
                       float* __restrict__ cvec)
{
  const int co = threadIdx.x;
  float s = 0.f;
  for (int f = 0; f < 512; f++) s += grn_b[f]*w2[f*128 + co];
  cvec[co] = s;
}

// ---------------------------------------------------------------------------
// K11: GEMM2  u[n,s,c] = t @ w2t_n^T + cvec, bf16 out + post-BN partials
// ---------------------------------------------------------------------------
__global__ __launch_bounds__(256) void k_gemm2(
    const ush* __restrict__ tbuf, const ush* __restrict__ w2t,
    const float* __restrict__ cvec, ush* __restrict__ u, float* __restrict__ upart)
{
  __shared__ __align__(16) ush Al[16384];
  __shared__ __align__(16) ush Bl[16384];
  const int mt = blockIdx.x, n = blockIdx.y, tid = threadIdx.x;
  const int wid = tid >> 6, lane = tid & 63;
  const int wm = wid >> 1, wn = wid & 1;
  const int lr = lane & 15, lk = lane >> 4;
  f32x4 acc[4][4] = {};
  #pragma unroll 1
  for (int kb = 0; kb < 4; kb++) {
    if (kb) __syncthreads();
    #pragma unroll
    for (int i = 0; i < 8; i++) {
      int g = i*256 + tid;
      int r = g >> 4, cg = g & 15;
      *(uint4*)&Al[r*128 + ((cg ^ (r & 7))*8)] =
        *(const uint4*)(tbuf + ((size_t)n*CS + (size_t)mt*128 + r)*512 + kb*128 + cg*8);
      *(uint4*)&Bl[r*128 + ((cg ^ (r & 7))*8)] =
        *(const uint4*)(w2t + ((size_t)n*128 + r)*512 + kb*128 + cg*8);
    }
    __syncthreads();
    #pragma unroll
    for (int kk = 0; kk < 4; kk++) {
      short8 af[4], bfr[4];
      #pragma unroll
      for (int mf = 0; mf < 4; mf++) {
        int row = wm*64 + mf*16 + lr;
        int cg = (kk*4 + lk) ^ (row & 7);
        af[mf] = *(const short8*)&Al[row*128 + cg*8];
      }
      #pragma unroll
      for (int nf = 0; nf < 4; nf++) {
        int row = wn*64 + nf*16 + lr;
        int cg = (kk*4 + lk) ^ (row & 7);
        bfr[nf] = *(const short8*)&Bl[row*128 + cg*8];
      }
      #pragma unroll
      for (int mf = 0; mf < 4; mf++)
        #pragma unroll
        for (int nf = 0; nf < 4; nf++)
          acc[mf][nf] = __builtin_amdgcn_mfma_f32_16x16x32_bf16(af[mf], bfr[nf], acc[mf][nf], 0, 0, 0);
    }
  }
  float cv[4];
  #pragma unroll
  for (int nf = 0; nf < 4; nf++) cv[nf] = cvec[wn*64 + nf*16 + lr];
  float su[4] = {0,0,0,0}, sq[4] = {0,0,0,0};
  #pragma unroll
  for (int mf = 0; mf < 4; mf++)
    #pragma unroll
    for (int nf = 0; nf < 4; nf++)
      #pragma unroll
      for (int r = 0; r < 4; r++) {
        float v = acc[mf][nf][r] + cv[nf];
        su[nf] += v; sq[nf] += v*v;
        acc[mf][nf][r] = v;
      }
  __syncthreads();
  float* stl = (float*)Al;
  #pragma unroll
  for (int nf = 0; nf < 4; nf++) {
    float a = su[nf]; a += __shfl_xor(a, 16); a += __shfl_xor(a, 32);
    float b = sq[nf]; b += __shfl_xor(b, 16); b += __shfl_xor(b, 32);
    if (lane < 16) {
      stl[((wn*64 + nf*16 + lane)*2 + wm)*2 + 0] = a;
      stl[((wn*64 + nf*16 + lane)*2 + wm)*2 + 1] = b;
    }
  }
  #pragma unroll
  for (int mf = 0; mf < 4; mf++)
    #pragma unroll
    for (int nf = 0; nf < 4; nf++)
      #pragma unroll
      for (int r = 0; r < 4; r++) {
        int ml = wm*64 + mf*16 + lk*4 + r;
        int fl = wn*64 + nf*16 + lr;
        Bl[ml*128 + (fl ^ (((ml >> 2) & 3) << 4))] = f2bf(acc[mf][nf][r]);
      }
  __syncthreads();
  #pragma unroll
  for (int i = 0; i < 8; i++) {
    int idx = i*256 + tid;
    int m = idx >> 4, gc = idx & 15;
    uint4 v = *(const uint4*)&Bl[m*128 + ((gc ^ (((m >> 2) & 3) << 1))*8)];
    *(uint4*)(u + ((size_t)n*CS + (size_t)mt*128 + m)*128 + gc*8) = v;
  }
  if (tid < 128) {
    float s = stl[(tid*2 + 0)*2 + 0] + stl[(tid*2 + 1)*2 + 0];
    float q = stl[(tid*2 + 0)*2 + 1] + stl[(tid*2 + 1)*2 + 1];
    upart[((size_t)(n*1024 + mt)*128 + tid)*2 + 0] = s;
    upart[((size_t)(n*1024 + mt)*128 + tid)*2 + 1] = q;
  }
}

// K12: post-BN stats -> P,Q per channel
__global__ __launch_bounds__(256) void k_pbn(
    const float* __restrict__ upart, const float* pbn_w, const float* pbn_b,
    const float* ls_g, float* __restrict__ PQ)
{
  __shared__ float rs[4], rq[4];
  const int c = blockIdx.x, tid = threadIdx.x;
  float s = 0.f, q = 0.f;
  for (int mtg = tid; mtg < 2048; mtg += 256) {
    s += upart[((size_t)mtg*128 + c)*2 + 0];
    q += upart[((size_t)mtg*128 + c)*2 + 1];
  }
  s = wave_sum(s); q = wave_sum(q);
  if ((tid & 63) == 0) { rs[tid >> 6] = s; rq[tid >> 6] = q; }
  __syncthreads();
  if (tid == 0) {
    float S = rs[0]+rs[1]+rs[2]+rs[3];
    float Qq = rq[0]+rq[1]+rq[2]+rq[3];
    float m = S*(1.f/262144.f);
    float var = Qq*(1.f/262144.f) - m*m;
    float inv = rsqrtf(var + BNEPS);
    PQ[c*2 + 0] = ls_g[c]*pbn_w[c]*inv;
    PQ[c*2 + 1] = ls_g[c]*(pbn_b[c] - m*inv*pbn_w[c]);
  }
}

// K13: out[n,c,s] = x + u[n,s,c]*P[c] + Q[c]
__global__ __launch_bounds__(256) void k_final(
    const ush* __restrict__ u, const float* __restrict__ x,
    const float* __restrict__ PQ, float* __restrict__ out)
{
  __shared__ ush ld[32768];
  __shared__ float Ps[128], Qs[128];
  const int sblk = blockIdx.x, n = blockIdx.y, tid = threadIdx.x;
  if (tid < 128) { Ps[tid] = PQ[tid*2]; Qs[tid] = PQ[tid*2 + 1]; }
  #pragma unroll 2
  for (int i = 0; i < 16; i++) {
    int idx = i*256 + tid;
    int s_l = idx >> 4, gc = idx & 15;
    *(uint4*)&ld[idx*8] = *(const uint4*)(u + ((size_t)n*CS + sblk*256 + s_l)*128 + gc*8);
  }
  __syncthreads();
  const int c = tid >> 1, sh = tid & 1;
  const float P = Ps[c], Q = Qs[c];
  const float* xp = x + ((size_t)(n*CC + c))*CS + sblk*256 + sh*128;
  float* op = out + ((size_t)(n*CC + c))*CS + sblk*256 + sh*128;
  #pragma unroll 4
  for (int j4 = 0; j4 < 32; j4++) {
    float4 xv = *(const float4*)(xp + j4*4);
    int s0 = sh*128 + j4*4;
    float4 ov;
    ov.x = xv.x + bf2f(ld[(s0+0)*128 + c])*P + Q;
    ov.y = xv.y + bf2f(ld[(s0+1)*128 + c])*P + Q;
    ov.z = xv.z + bf2f(ld[(s0+2)*128 + c])*P + Q;
    ov.w = xv.w + bf2f(ld[(s0+3)*128 + c])*P + Q;
    *(float4*)(op + j4*4) = ov;
  }
}

// ---------------------------------------------------------------------------
extern "C" void kernel_launch(void* const* d_in, const int* in_sizes, int n_in,
                              void* d_out, int out_size, void* d_ws, size_t ws_size,
                              hipStream_t stream)
{
  (void)in_sizes; (void)n_in; (void)out_size; (void)ws_size;
  const float* x      = (const float*)d_in[0];
  const float* lk_w   = (const float*)d_in[1];
  const float* bn0_w  = (const float*)d_in[2];
  const float* bn0_b  = (const float*)d_in[3];
  const float* dw5_w  = (const float*)d_in[4];
  const float* dbn1_w = (const float*)d_in[5];
  const float* dbn1_b = (const float*)d_in[6];
  const float* dw3a_w = (const float*)d_in[7];
  const float* dbn2_w = (const float*)d_in[8];
  const float* dbn2_b = (const float*)d_in[9];
  const float* dw3b_w = (const float*)d_in[10];
  const float* dbn3_w = (const float*)d_in[11];
  const float* dbn3_b = (const float*)d_in[12];
  const float* nrm_w  = (const float*)d_in[13];
  const float* nrm_b  = (const float*)d_in[14];
  const float* se_dw  = (const float*)d_in[15];
  const float* se_db  = (const float*)d_in[16];
  const float* se_uw  = (const float*)d_in[17];
  const float* se_ub  = (const float*)d_in[18];
  const float* w1     = (const float*)d_in[19];
  const float* b1     = (const float*)d_in[20];
  const float* grn_g  = (const float*)d_in[21];
  const float* grn_b  = (const float*)d_in[22];
  const float* w2     = (const float*)d_in[23];
  const float* pbn_w  = (const float*)d_in[24];
  const float* pbn_b  = (const float*)d_in[25];
  const float* ls_g   = (const float*)d_in[26];

  char* w = (char*)d_ws;
  size_t cur = 0;
  auto take = [&](size_t b) { size_t r = cur; cur += (b + 255) & ~(size_t)255; return r; };
  ush*   y_pre = (ush*)  (w + take((size_t)2*CC*CS*2));
  float* part1 = (float*)(w + take(4096*8*4));
  float* part2 = (float*)(w + take(4096*2*4));
  float* coef3 = (float*)(w + take(128*49*4*4));
  float* Tbuf  = (float*)(w + take(128*4));
  float* ABuf  = (float*)(w + take(2*128*2*4));
  ush*   w1t   = (ush*)  (w + take(2*512*128*2));
  float* beta  = (float*)(w + take(2*512*4));
  float* grnp  = (float*)(w + take((size_t)1024*1024*4));
  float* aBuf  = (float*)(w + take(2*512*4));
  ush*   w2t   = (ush*)  (w + take(2*128*512*2));
  float* cvec  = (float*)(w + take(128*4));
  float* upart = (float*)(w + take((size_t)2048*128*2*4));
  float* PQ    = (float*)(w + take(128*2*4));
  ush*   tbuf  = (ush*)  (w + take((size_t)2*CS*512*2));
  ush*   u_buf = y_pre;
  ush*   y_cl  = (ush*)d_out;
  float* outp  = (float*)d_out;

  k_conv_stats<<<dim3(16,128,2), 256, 0, stream>>>(x, lk_w, dw5_w, dw3a_w, dw3b_w, part1);
  k_branch_reduce<<<1, 512, 0, stream>>>(part1, bn0_w, bn0_b, dbn1_w, dbn1_b,
                                         dbn2_w, dbn2_b, dbn3_w, dbn3_b,
                                         lk_w, dw5_w, dw3a_w, dw3b_w, coef3, Tbuf);
  k_conv_main<<<dim3(16,128,2), 256, 0, stream>>>(x, coef3, Tbuf, y_pre, part2);
  k_bn_se<<<1, 256, 0, stream>>>(part2, nrm_w, nrm_b, se_dw, se_db, se_uw, se_ub, ABuf);
  k_w1prep<<<2, 512, 0, stream>>>(w1, b1, ABuf, w1t, beta);
  k_transpose<<<dim3(512,2), 256, 0, stream>>>(y_pre, y_cl);
  k_gemm1<<<dim3(1024,4,2), 256, 0, stream>>>(y_cl, w1t, beta, tbuf, grnp);
  k_grn<<<1, 1024, 0, stream>>>(grnp, grn_g, aBuf);
  k_w2prep<<<2, 512, 0, stream>>>(w2, aBuf, w2t);
  k_cvec<<<1, 128, 0, stream>>>(w2, grn_b, cvec);
  k_gemm2<<<dim3(1024,2), 256, 0, stream>>>(tbuf, w2t, cvec, u_buf, upart);
  k_pbn<<<128, 256, 0, stream>>>(upart, pbn_w, pbn_b, ls_g, PQ);
  k_final<<<dim3(512,2), 256, 0, stream>>>(u_buf, x, PQ, outp);
}